// Round 1
// baseline (639.339 us; speedup 1.0000x reference)
//
#include <hip/hip_runtime.h>

#define B_ 256
#define U_ 512
#define NG 2048   // 4*U

__device__ __forceinline__ float hsig(float z) {
    return fminf(fmaxf(0.2f * z + 0.5f, 0.f), 1.f);
}

// ---------------------------------------------------------------------------
// Kernel A: preact[b][g*U+v] = x@kernel + bias + h_tm1@R'
//   R'[:, 0:U]   = rec_kernel[:, 0:U]      (i gate)
//   R'[:, U:2U]  = rec_kernel[:, U:2U]     (f gate)
//   R'[:, 2U:3U] = w                       (cell path: h@w)
//   R'[:, 3U:4U] = rec_kernel[:, 3U:4U]    (o gate)
// 64x64 tile, BK=16, 256 threads, 4x4 microtile.
// ---------------------------------------------------------------------------
__global__ __launch_bounds__(256) void gemm_preact(
    const float* __restrict__ x, const float* __restrict__ h,
    const float* __restrict__ kern, const float* __restrict__ reck,
    const float* __restrict__ w, const float* __restrict__ bias,
    float* __restrict__ preact)
{
    __shared__ float As[64][20];   // padded
    __shared__ float Bs[16][64];
    const int tid = threadIdx.x;
    const int tx = tid & 15, ty = tid >> 4;
    const int m0 = blockIdx.y * 64;
    const int n0 = blockIdx.x * 64;
    float acc[4][4] = {};

    for (int phase = 0; phase < 2; ++phase) {
        const float* A = phase ? h : x;          // [256][512]
        const float* Bp;
        int bstride;
        if (phase == 0)                { Bp = kern + n0;          bstride = NG; }
        else if (n0 >= 2*U_ && n0 < 3*U_) { Bp = w + (n0 - 2*U_); bstride = U_; }
        else                           { Bp = reck + n0;          bstride = NG; }

        for (int k0 = 0; k0 < 512; k0 += 16) {
            {
                const int row = tid >> 2;           // 0..63
                const int kk  = (tid & 3) * 4;      // 0,4,8,12
                float4 a4 = *(const float4*)(A + (size_t)(m0 + row) * 512 + k0 + kk);
                *(float4*)&As[row][kk] = a4;
            }
            {
                const int kk  = tid >> 4;           // 0..15
                const int col = (tid & 15) * 4;
                float4 b4 = *(const float4*)(Bp + (size_t)(k0 + kk) * bstride + col);
                *(float4*)&Bs[kk][col] = b4;
            }
            __syncthreads();
            #pragma unroll
            for (int kk = 0; kk < 16; ++kk) {
                float a0 = As[ty*4+0][kk], a1 = As[ty*4+1][kk];
                float a2 = As[ty*4+2][kk], a3 = As[ty*4+3][kk];
                float b0 = Bs[kk][tx*4+0], b1 = Bs[kk][tx*4+1];
                float b2 = Bs[kk][tx*4+2], b3 = Bs[kk][tx*4+3];
                acc[0][0] = fmaf(a0,b0,acc[0][0]); acc[0][1] = fmaf(a0,b1,acc[0][1]);
                acc[0][2] = fmaf(a0,b2,acc[0][2]); acc[0][3] = fmaf(a0,b3,acc[0][3]);
                acc[1][0] = fmaf(a1,b0,acc[1][0]); acc[1][1] = fmaf(a1,b1,acc[1][1]);
                acc[1][2] = fmaf(a1,b2,acc[1][2]); acc[1][3] = fmaf(a1,b3,acc[1][3]);
                acc[2][0] = fmaf(a2,b0,acc[2][0]); acc[2][1] = fmaf(a2,b1,acc[2][1]);
                acc[2][2] = fmaf(a2,b2,acc[2][2]); acc[2][3] = fmaf(a2,b3,acc[2][3]);
                acc[3][0] = fmaf(a3,b0,acc[3][0]); acc[3][1] = fmaf(a3,b1,acc[3][1]);
                acc[3][2] = fmaf(a3,b2,acc[3][2]); acc[3][3] = fmaf(a3,b3,acc[3][3]);
            }
            __syncthreads();
        }
    }
    #pragma unroll
    for (int i = 0; i < 4; ++i) {
        const int row = m0 + ty*4 + i;
        const int col = n0 + tx*4;
        float4 o;
        o.x = acc[i][0] + bias[col+0];
        o.y = acc[i][1] + bias[col+1];
        o.z = acc[i][2] + bias[col+2];
        o.w = acc[i][3] + bias[col+3];
        *(float4*)(preact + (size_t)row * NG + col) = o;
    }
}

// ---------------------------------------------------------------------------
// Kernel B: hebbsum[b][v] += sum_u h_tm1[b][u] * hebb[b][u][v]
// grid (256, 4): b x u-chunk(128). 256 thr: lane = v-float4 (128) x u-group(2).
// ---------------------------------------------------------------------------
__global__ __launch_bounds__(256) void hebb_reduce(
    const float* __restrict__ hebb, const float* __restrict__ h_tm1,
    float* __restrict__ hebbsum)
{
    const int b   = blockIdx.x;
    const int us  = blockIdx.y;
    const int tid = threadIdx.x;
    const int vl  = tid & 127;
    const int ug  = tid >> 7;
    const int v   = vl * 4;

    __shared__ float hsh[128];
    if (tid < 128) hsh[tid] = h_tm1[b * 512 + us * 128 + tid];
    __syncthreads();

    const float* hb = hebb + ((size_t)b * 512 + us * 128 + ug) * 512 + v;
    float4 acc = make_float4(0.f, 0.f, 0.f, 0.f);
    #pragma unroll 4
    for (int i = 0; i < 64; ++i) {
        const float hs = hsh[i * 2 + ug];
        float4 hv = *(const float4*)(hb + (size_t)i * 1024);
        acc.x = fmaf(hs, hv.x, acc.x);
        acc.y = fmaf(hs, hv.y, acc.y);
        acc.z = fmaf(hs, hv.z, acc.z);
        acc.w = fmaf(hs, hv.w, acc.w);
    }

    __shared__ float4 red[128];
    if (ug) red[vl] = acc;
    __syncthreads();
    if (!ug) {
        float4 o = red[vl];
        float* dst = hebbsum + b * 512 + v;
        atomicAdd(dst + 0, acc.x + o.x);
        atomicAdd(dst + 1, acc.y + o.y);
        atomicAdd(dst + 2, acc.z + o.z);
        atomicAdd(dst + 3, acc.w + o.w);
    }
}

// ---------------------------------------------------------------------------
// Kernel C: gates, c, h, itc, etab[b] = tanh(h . h2mod)
// one block of 512 threads per b
// ---------------------------------------------------------------------------
__global__ __launch_bounds__(512) void cell_kernel(
    const float* __restrict__ preact, const float* __restrict__ hebbsum,
    const float* __restrict__ alpha, const float* __restrict__ c_tm1,
    const float* __restrict__ h2mod,
    float* __restrict__ out_h, float* __restrict__ out_c,
    float* __restrict__ itc_ws, float* __restrict__ etab_ws)
{
    const int b = blockIdx.x;
    const int v = threadIdx.x;
    const float* pr = preact + (size_t)b * NG;
    const float pi = pr[v], pf = pr[512 + v], pc = pr[1024 + v], po = pr[1536 + v];

    const float h2c = fmaf(alpha[v], hebbsum[b * 512 + v], pc);
    const float itc = tanhf(h2c);
    const float gi = hsig(pi), gf = hsig(pf), go = hsig(po);
    const float c  = gf * c_tm1[b * 512 + v] + gi * itc;
    const float hh = go * tanhf(c);

    out_h[b * 512 + v]  = hh;
    out_c[b * 512 + v]  = c;
    itc_ws[b * 512 + v] = itc;

    float d = hh * h2mod[v];
    #pragma unroll
    for (int off = 32; off > 0; off >>= 1) d += __shfl_down(d, off, 64);
    __shared__ float wred[8];
    if ((v & 63) == 0) wred[v >> 6] = d;
    __syncthreads();
    if (v == 0) {
        float s = 0.f;
        #pragma unroll
        for (int k = 0; k < 8; ++k) s += wred[k];
        etab_ws[b] = tanhf(s);
    }
}

// ---------------------------------------------------------------------------
// Kernel D: hebb_new[b][u][v] = clip(hebb + etab[b]*fanout[v]*itc[b][v]*h[b][u], +-2)
// same geometry as kernel B
// ---------------------------------------------------------------------------
__global__ __launch_bounds__(256) void hebb_update(
    const float* __restrict__ hebb, const float* __restrict__ h_tm1,
    const float* __restrict__ itc_ws, const float* __restrict__ fanout,
    const float* __restrict__ etab_ws, float* __restrict__ out_hebb)
{
    const int b   = blockIdx.x;
    const int us  = blockIdx.y;
    const int tid = threadIdx.x;
    const int vl  = tid & 127;
    const int ug  = tid >> 7;
    const int v   = vl * 4;

    __shared__ float hsh[128];
    if (tid < 128) hsh[tid] = h_tm1[b * 512 + us * 128 + tid];
    __syncthreads();

    const float eta = etab_ws[b];
    float4 fv = *(const float4*)(fanout + v);
    float4 iv = *(const float4*)(itc_ws + b * 512 + v);
    float4 ef;
    ef.x = eta * fv.x * iv.x; ef.y = eta * fv.y * iv.y;
    ef.z = eta * fv.z * iv.z; ef.w = eta * fv.w * iv.w;

    const size_t base = ((size_t)b * 512 + us * 128 + ug) * 512 + v;
    #pragma unroll 4
    for (int i = 0; i < 64; ++i) {
        const float hs = hsh[i * 2 + ug];
        float4 hv = *(const float4*)(hebb + base + (size_t)i * 1024);
        float4 o;
        o.x = fminf(fmaxf(fmaf(ef.x, hs, hv.x), -2.f), 2.f);
        o.y = fminf(fmaxf(fmaf(ef.y, hs, hv.y), -2.f), 2.f);
        o.z = fminf(fmaxf(fmaf(ef.z, hs, hv.z), -2.f), 2.f);
        o.w = fminf(fmaxf(fmaf(ef.w, hs, hv.w), -2.f), 2.f);
        *(float4*)(out_hebb + base + (size_t)i * 1024) = o;
    }
}

extern "C" void kernel_launch(void* const* d_in, const int* in_sizes, int n_in,
                              void* d_out, int out_size, void* d_ws, size_t ws_size,
                              hipStream_t stream)
{
    const float* x      = (const float*)d_in[0];
    const float* h_tm1  = (const float*)d_in[1];
    const float* c_tm1  = (const float*)d_in[2];
    const float* hebb   = (const float*)d_in[3];
    const float* kern   = (const float*)d_in[4];
    const float* reck   = (const float*)d_in[5];
    const float* bias   = (const float*)d_in[6];
    const float* w      = (const float*)d_in[7];
    const float* alpha  = (const float*)d_in[8];
    const float* h2mod  = (const float*)d_in[9];
    const float* fanout = (const float*)d_in[10];

    float* out_h    = (float*)d_out;
    float* out_c    = out_h + (size_t)B_ * U_;
    float* out_hebb = out_c + (size_t)B_ * U_;

    float* ws       = (float*)d_ws;
    float* hebbsum  = ws;                          // B*U
    float* itc      = ws + (size_t)B_ * U_;        // B*U
    float* etab     = ws + (size_t)2 * B_ * U_;    // B
    float* preact   = ws + (size_t)2 * B_ * U_ + 256; // B*NG

    hipMemsetAsync(hebbsum, 0, (size_t)B_ * U_ * sizeof(float), stream);
    gemm_preact<<<dim3(32, 4), 256, 0, stream>>>(x, h_tm1, kern, reck, w, bias, preact);
    hebb_reduce<<<dim3(256, 4), 256, 0, stream>>>(hebb, h_tm1, hebbsum);
    cell_kernel<<<256, 512, 0, stream>>>(preact, hebbsum, alpha, c_tm1, h2mod,
                                         out_h, out_c, itc, etab);
    hebb_update<<<dim3(256, 4), 256, 0, stream>>>(hebb, h_tm1, itc, fanout, etab, out_hebb);
}

// Round 2
// 596.952 us; speedup vs baseline: 1.0710x; 1.0710x over previous
//
#include <hip/hip_runtime.h>

#define B_ 256
#define U_ 512
#define NG 2048   // 4*U

__device__ __forceinline__ float hsig(float z) {
    return fminf(fmaxf(0.2f * z + 0.5f, 0.f), 1.f);
}

// ---------------------------------------------------------------------------
// Kernel 1 (fused): blocks 0..127 -> GEMM  preact = x@kernel + bias + h@R'
//                   blocks 128..1151 -> hebb partial reduce
//   R'[:, 2U:3U] = w (cell path uses h@w), other quarters = rec_kernel.
// GEMM: 64x64 tile, BK=16, 256 thr, 4x4 microtile, transposed-A LDS so the
// inner loop is 2x ds_read_b128 + 16 FMA per k-step.
// Reduce: block (b, us) sums 128 u-rows of hebb into partial[us][b][v]
// (private slice -> no memset, no atomics).
// ---------------------------------------------------------------------------
__global__ __launch_bounds__(256) void fused_gemm_reduce(
    const float* __restrict__ x, const float* __restrict__ h,
    const float* __restrict__ kern, const float* __restrict__ reck,
    const float* __restrict__ w, const float* __restrict__ bias,
    const float* __restrict__ hebb,
    float* __restrict__ preact, float* __restrict__ partial)
{
    const int tid = threadIdx.x;

    if (blockIdx.x < 128) {
        // ---------------- GEMM role ----------------
        __shared__ float As[16][68];   // [k][m]  (transposed)
        __shared__ float Bs[16][68];   // [k][n]
        const int gb = blockIdx.x;
        const int n0 = (gb & 31) * 64;
        const int m0 = (gb >> 5) * 64;
        const int tx = tid & 15, ty = tid >> 4;
        float acc[4][4] = {};

        for (int phase = 0; phase < 2; ++phase) {
            const float* A = phase ? h : x;          // [256][512]
            const float* Bp;
            int bstride;
            if (phase == 0)                     { Bp = kern + n0;         bstride = NG; }
            else if (n0 >= 2*U_ && n0 < 3*U_)   { Bp = w + (n0 - 2*U_);   bstride = U_; }
            else                                { Bp = reck + n0;         bstride = NG; }

            for (int k0 = 0; k0 < 512; k0 += 16) {
                {   // stage A transposed
                    const int row = tid >> 2;          // 0..63 (m)
                    const int kq  = (tid & 3) * 4;     // 0,4,8,12
                    float4 a4 = *(const float4*)(A + (size_t)(m0 + row) * 512 + k0 + kq);
                    As[kq+0][row] = a4.x; As[kq+1][row] = a4.y;
                    As[kq+2][row] = a4.z; As[kq+3][row] = a4.w;
                }
                {   // stage B
                    const int kk  = tid >> 4;          // 0..15
                    const int col = (tid & 15) * 4;
                    float4 b4 = *(const float4*)(Bp + (size_t)(k0 + kk) * bstride + col);
                    *(float4*)&Bs[kk][col] = b4;
                }
                __syncthreads();
                #pragma unroll
                for (int kk = 0; kk < 16; ++kk) {
                    float4 a4 = *(const float4*)&As[kk][ty*4];
                    float4 b4 = *(const float4*)&Bs[kk][tx*4];
                    const float a[4] = {a4.x, a4.y, a4.z, a4.w};
                    const float b[4] = {b4.x, b4.y, b4.z, b4.w};
                    #pragma unroll
                    for (int i = 0; i < 4; ++i) {
                        acc[i][0] = fmaf(a[i], b[0], acc[i][0]);
                        acc[i][1] = fmaf(a[i], b[1], acc[i][1]);
                        acc[i][2] = fmaf(a[i], b[2], acc[i][2]);
                        acc[i][3] = fmaf(a[i], b[3], acc[i][3]);
                    }
                }
                __syncthreads();
            }
        }
        #pragma unroll
        for (int i = 0; i < 4; ++i) {
            const int row = m0 + ty*4 + i;
            const int col = n0 + tx*4;
            float4 o;
            o.x = acc[i][0] + bias[col+0];
            o.y = acc[i][1] + bias[col+1];
            o.z = acc[i][2] + bias[col+2];
            o.w = acc[i][3] + bias[col+3];
            *(float4*)(preact + (size_t)row * NG + col) = o;
        }
    } else {
        // ---------------- hebb reduce role ----------------
        __shared__ float  hsh[128];
        __shared__ float4 red[128];
        const int rid = blockIdx.x - 128;
        const int b   = rid >> 2;
        const int us  = rid & 3;
        const int vl  = tid & 127;
        const int ug  = tid >> 7;
        const int v   = vl * 4;

        if (tid < 128) hsh[tid] = h[b * 512 + us * 128 + tid];
        __syncthreads();

        const float* hb = hebb + ((size_t)b * 512 + us * 128 + ug) * 512 + v;
        float4 acc = make_float4(0.f, 0.f, 0.f, 0.f);
        #pragma unroll 8
        for (int i = 0; i < 64; ++i) {
            const float hs = hsh[i * 2 + ug];
            float4 hv = *(const float4*)(hb + (size_t)i * 1024);
            acc.x = fmaf(hs, hv.x, acc.x);
            acc.y = fmaf(hs, hv.y, acc.y);
            acc.z = fmaf(hs, hv.z, acc.z);
            acc.w = fmaf(hs, hv.w, acc.w);
        }

        if (ug) red[vl] = acc;
        __syncthreads();
        if (!ug) {
            float4 o = red[vl];
            o.x += acc.x; o.y += acc.y; o.z += acc.z; o.w += acc.w;
            *(float4*)(partial + ((size_t)us * 256 + b) * 512 + v) = o;
        }
    }
}

// ---------------------------------------------------------------------------
// Kernel 2 (fused cell + hebb update). grid (256,4): b x u-chunk(128).
// Each block recomputes the cell math for its b (cheap, L2-hot), derives
// eta in-block; us==0 writes h/c; then streams its hebb chunk update.
// ---------------------------------------------------------------------------
__global__ __launch_bounds__(256) void cell_update(
    const float* __restrict__ preact, const float* __restrict__ partial,
    const float* __restrict__ alpha, const float* __restrict__ c_tm1,
    const float* __restrict__ h_tm1, const float* __restrict__ h2mod,
    const float* __restrict__ fanout, const float* __restrict__ hebb,
    float* __restrict__ out_h, float* __restrict__ out_c,
    float* __restrict__ out_hebb)
{
    const int b   = blockIdx.x;
    const int us  = blockIdx.y;
    const int tid = threadIdx.x;

    __shared__ float itc_sh[512];
    __shared__ float hsh[128];
    __shared__ float wred[4];
    __shared__ float eta_sh;

    // ---- cell phase: 2 v's per thread ----
    const float* pr = preact + (size_t)b * NG;
    float hv2[2];
    #pragma unroll
    for (int s = 0; s < 2; ++s) {
        const int v = tid + s * 256;
        const float hsum = partial[(0*256 + b) * 512 + v]
                         + partial[(1*256 + b) * 512 + v]
                         + partial[(2*256 + b) * 512 + v]
                         + partial[(3*256 + b) * 512 + v];
        const float itc = tanhf(fmaf(alpha[v], hsum, pr[1024 + v]));
        const float gi = hsig(pr[v]);
        const float gf = hsig(pr[512 + v]);
        const float go = hsig(pr[1536 + v]);
        const float c  = gf * c_tm1[b * 512 + v] + gi * itc;
        const float hh = go * tanhf(c);
        itc_sh[v] = itc;
        hv2[s] = hh;
        if (us == 0) {
            out_h[b * 512 + v] = hh;
            out_c[b * 512 + v] = c;
        }
    }
    if (tid < 128) hsh[tid] = h_tm1[b * 512 + us * 128 + tid];

    // ---- eta = tanh(h . h2mod) ----
    float d = hv2[0] * h2mod[tid] + hv2[1] * h2mod[tid + 256];
    #pragma unroll
    for (int off = 32; off > 0; off >>= 1) d += __shfl_down(d, off, 64);
    if ((tid & 63) == 0) wred[tid >> 6] = d;
    __syncthreads();
    if (tid == 0) eta_sh = tanhf(wred[0] + wred[1] + wred[2] + wred[3]);
    __syncthreads();
    const float eta = eta_sh;

    // ---- update phase ----
    const int vl = tid & 127;
    const int ug = tid >> 7;
    const int v  = vl * 4;

    float4 fv = *(const float4*)(fanout + v);
    float4 ef;
    ef.x = eta * fv.x * itc_sh[v + 0];
    ef.y = eta * fv.y * itc_sh[v + 1];
    ef.z = eta * fv.z * itc_sh[v + 2];
    ef.w = eta * fv.w * itc_sh[v + 3];

    const size_t base = ((size_t)b * 512 + us * 128 + ug) * 512 + v;
    #pragma unroll 8
    for (int i = 0; i < 64; ++i) {
        const float hs = hsh[i * 2 + ug];
        float4 hv = *(const float4*)(hebb + base + (size_t)i * 1024);
        float4 o;
        o.x = fminf(fmaxf(fmaf(ef.x, hs, hv.x), -2.f), 2.f);
        o.y = fminf(fmaxf(fmaf(ef.y, hs, hv.y), -2.f), 2.f);
        o.z = fminf(fmaxf(fmaf(ef.z, hs, hv.z), -2.f), 2.f);
        o.w = fminf(fmaxf(fmaf(ef.w, hs, hv.w), -2.f), 2.f);
        *(float4*)(out_hebb + base + (size_t)i * 1024) = o;
    }
}

extern "C" void kernel_launch(void* const* d_in, const int* in_sizes, int n_in,
                              void* d_out, int out_size, void* d_ws, size_t ws_size,
                              hipStream_t stream)
{
    const float* x      = (const float*)d_in[0];
    const float* h_tm1  = (const float*)d_in[1];
    const float* c_tm1  = (const float*)d_in[2];
    const float* hebb   = (const float*)d_in[3];
    const float* kern   = (const float*)d_in[4];
    const float* reck   = (const float*)d_in[5];
    const float* bias   = (const float*)d_in[6];
    const float* w      = (const float*)d_in[7];
    const float* alpha  = (const float*)d_in[8];
    const float* h2mod  = (const float*)d_in[9];
    const float* fanout = (const float*)d_in[10];

    float* out_h    = (float*)d_out;
    float* out_c    = out_h + (size_t)B_ * U_;
    float* out_hebb = out_c + (size_t)B_ * U_;

    float* ws      = (float*)d_ws;
    float* partial = ws;                                   // 4*B*U floats
    float* preact  = ws + (size_t)4 * B_ * U_;             // B*NG floats

    fused_gemm_reduce<<<128 + 1024, 256, 0, stream>>>(
        x, h_tm1, kern, reck, w, bias, hebb, preact, partial);
    cell_update<<<dim3(256, 4), 256, 0, stream>>>(
        preact, partial, alpha, c_tm1, h_tm1, h2mod, fanout, hebb,
        out_h, out_c, out_hebb);
}